// Round 5
// baseline (55.128 us; speedup 1.0000x reference)
//
#include <hip/hip_runtime.h>
#include <hip/hip_bf16.h>
#include <math.h>

constexpr int T = 128;
constexpr int B = 128;
constexpr int R = 512;
constexpr int NS = 256;   // 2*T slots

typedef __attribute__((ext_vector_type(8))) short bf16x8;
typedef __attribute__((ext_vector_type(4))) float f32x4;

static __device__ __forceinline__ ushort f2bf(float f) {
    union { float f; unsigned u; } v; v.f = f;
    unsigned r = v.u + 0x7fffu + ((v.u >> 16) & 1u);   // RNE
    return (ushort)(r >> 16);
}

// ---------------------------------------------------------------------------
// Kernel 1: closed-form weights, bf16 output. Block = one t, 256 threads.
// (unchanged from round 4 — measured fast enough; GEMM is the target)
// ---------------------------------------------------------------------------
__global__ __launch_bounds__(256) void weights(
    const float* __restrict__ u, const float* __restrict__ d1,
    const float* __restrict__ d2, ushort* __restrict__ w)
{
    const int t    = blockIdx.x;
    const int tid  = threadIdx.x;
    const int wv   = tid >> 6;
    const int lane = tid & 63;
    __shared__ float eH[T][B];   // 64 KB: e, overwritten with H

    const int nfl = t * B;
    for (int i = tid * 4; i < nfl; i += 1024) {
        const float4 a  = *(const float4*)(d1 + i);
        const float4 b4 = *(const float4*)(d2 + i);
        const float4 c4 = *(const float4*)(u + i);
        *(float4*)(&eH[0][0] + i) =
            make_float4(a.x + b4.x - c4.x, a.y + b4.y - c4.y,
                        a.z + b4.z - c4.z, a.w + b4.w - c4.w);
    }
    __syncthreads();

    if (tid < B) {
        float h = 0.f;
        #pragma unroll 4
        for (int tt = 0; tt < t; ++tt) {
            h = fmaxf(0.f, h + eH[tt][tid]);
            eH[tt][tid] = h;
        }
    }
    __syncthreads();

    const int b0 = lane, b1 = lane + 64;
    const float Ht1a = (t > 0) ? eH[t-1][b0] : 0.f;
    const float Ht1b = (t > 0) ? eH[t-1][b1] : 0.f;
    const float Hpa  = Ht1a + d1[t*B+b0] + d2[t*B+b0];   // H'_t
    const float Hpb  = Ht1b + d1[t*B+b1] + d2[t*B+b1];
    const float Aa   = u[t*B+b0] - Hpa;
    const float Ab   = u[t*B+b1] - Hpb;

    ushort* wrow0 = w + ((size_t)t * B + b0) * NS;
    ushort* wrow1 = w + ((size_t)t * B + b1) * NS;

    const int plo = wv * 32;
    if (plo <= t) {
        const int pe = min(plo + 31, t);
        float ma = 1e30f, mb = 1e30f;
        for (int tau = plo + 32; tau <= t - 1; ++tau) {    // boundary min
            ma = fminf(ma, eH[tau][b0]);
            mb = fminf(mb, eH[tau][b1]);
        }
        float s2a = 0.f, s3a = 0.f, s2b = 0.f, s3b = 0.f;
        float nd1a = d1[pe*B+b0], nd1b = d1[pe*B+b1];
        float nd2a = d2[pe*B+b0], nd2b = d2[pe*B+b1];
        for (int p = pe; p >= plo; --p) {
            const float d1a = nd1a, d1b = nd1b, d2a = nd2a, d2b = nd2b;
            if (p > plo) {
                nd1a = d1[(p-1)*B+b0]; nd1b = d1[(p-1)*B+b1];
                nd2a = d2[(p-1)*B+b0]; nd2b = d2[(p-1)*B+b1];
            }
            if (p < t) { ma = fminf(ma, eH[p][b0]); mb = fminf(mb, eH[p][b1]); }
            const float basea = (p > 0) ? eH[p-1][b0] : 0.f;
            const float baseb = (p > 0) ? eH[p-1][b1] : 0.f;
            const float top0a = basea + d1a, top0b = baseb + d1b;
            const float top1a = top0a + d2a, top1b = top0b + d2b;

            const float sa0 = fminf(fmaxf(ma - basea, 0.f), d1a);
            const float sb0 = fminf(fmaxf(mb - baseb, 0.f), d1b);
            const float sa1 = fminf(fmaxf(ma - top0a, 0.f), d2a);
            const float sb1 = fminf(fmaxf(mb - top0b, 0.f), d2b);

            float cand0 = fmaxf(Aa + fminf(top0a, ma), Ab + fminf(top0b, mb));
            float cand1 = fmaxf(Aa + fminf(top1a, ma), Ab + fminf(top1b, mb));
            #pragma unroll
            for (int off = 32; off >= 1; off >>= 1) {
                cand0 = fmaxf(cand0, __shfl_xor(cand0, off));
                cand1 = fmaxf(cand1, __shfl_xor(cand1, off));
            }

            const float w0a = fminf(sa0, cand0), w0b = fminf(sb0, cand0);
            const float w1a = fminf(sa1, cand1), w1b = fminf(sb1, cand1);
            if (p & 1) { s2a = w0a; s3a = w1a; s2b = w0b; s3b = w1b; }
            else {
                const int g = p >> 1;
                *(ushort4*)(wrow0 + 4*g) =
                    make_ushort4(f2bf(w0a), f2bf(w1a), f2bf(s2a), f2bf(s3a));
                *(ushort4*)(wrow1 + 4*g) =
                    make_ushort4(f2bf(w0b), f2bf(w1b), f2bf(s2b), f2bf(s3b));
            }
        }
    }

    const int gstart = (t >> 1) + 1;
    const int ng = (NS / 4) - gstart;
    if (ng > 0) {
        const ushort4 z = make_ushort4(0, 0, 0, 0);
        const int total = ng * B;
        for (int idx = tid; idx < total; idx += 256) {
            const int gi = idx % ng;
            const int bb = idx / ng;
            *(ushort4*)(w + ((size_t)t*B + bb)*NS + 4*(gstart + gi)) = z;
        }
    }
}

// ---------------------------------------------------------------------------
// Kernel 2: bf16 MFMA GEMM, A direct-from-global, V double-staged.
// Out[t,b,r] = sum_j w[t,b,j] * V[j,b,r]; V interleaved from v1/v2.
// Block = (b, r-tile 64), grid 1024 = 4 blocks/CU. 256 thr = 4 waves;
// wave wv owns t in [32wv, 32wv+32). Only Bs (V) staged in LDS (4x reuse);
// A fragments are contiguous 16B in w -> loaded straight to VGPRs.
// V loads issued 3 chunks ahead of their LDS write (2 register sets).
// Zero-structure: wave wv skips A-load+MFMA for chunk c > 2wv+1.
// ---------------------------------------------------------------------------
#define RT 64
__global__ __launch_bounds__(256) void gemm_mfma(
    const ushort* __restrict__ w, const float* __restrict__ v1,
    const float* __restrict__ v2, float* __restrict__ out)
{
    const int b    = blockIdx.x;
    const int r0   = blockIdx.y * RT;
    const int tid  = threadIdx.x;
    const int wv   = tid >> 6;
    const int lane = tid & 63;

    __shared__ ushort Bs[2][RT][40];   // 10.2 KB total

    // B staging: thread = (slot-pair p2, r-quad rh)
    const int p2 = tid & 15;
    const int rh = tid >> 4;           // 0..15 -> r offset rh*4
    const float* v1b = v1 + (size_t)b * R + r0 + rh * 4;
    const float* v2b = v2 + (size_t)b * R + r0 + rh * 4;

    // A fragments: lane row tb, k-offset ko
    const int tb = wv * 32 + (lane & 15);
    const int ko = (lane >> 4) * 8;
    const ushort* arow0 = w + ((size_t)tb * B + b) * NS + ko;
    const ushort* arow1 = w + ((size_t)(tb + 16) * B + b) * NS + ko;

    const int climit = 2 * wv + 1;     // chunks c <= climit have nonzero A

    f32x4 acc0[4], acc1[4];
    const f32x4 zz = {0.f, 0.f, 0.f, 0.f};
    #pragma unroll
    for (int i = 0; i < 4; ++i) { acc0[i] = zz; acc1[i] = zz; }

    float4 sv1[2], sv2[2];
    bf16x8 af0[2], af1[2];

    #define VLOAD(s, k) do {                                            \
        if ((k) < 8) {                                                  \
            const size_t off_ = (size_t)((k) * 16 + p2) * B * R;        \
            sv1[s] = *(const float4*)(v1b + off_);                      \
            sv2[s] = *(const float4*)(v2b + off_);                      \
        }                                                               \
    } while (0)

    #define BW(buf, s) do {                                             \
        const float* f1_ = (const float*)&sv1[s];                       \
        const float* f2_ = (const float*)&sv2[s];                       \
        _Pragma("unroll")                                               \
        for (int i_ = 0; i_ < 4; ++i_) {                                \
            unsigned pk_ = (unsigned)f2bf(f1_[i_]) |                    \
                           ((unsigned)f2bf(f2_[i_]) << 16);             \
            *(unsigned*)&Bs[buf][rh * 4 + i_][p2 * 2] = pk_;            \
        }                                                               \
    } while (0)

    #define ALOAD(s, k) do {                                            \
        if ((k) < 8 && (k) <= climit) {                                 \
            af0[s] = *(const bf16x8*)(arow0 + (k) * 32);                \
            af1[s] = *(const bf16x8*)(arow1 + (k) * 32);                \
        }                                                               \
    } while (0)

    VLOAD(0, 0);
    BW(0, 0);          // Bs[0] <- chunk 0 (compiler inserts vmcnt wait)
    VLOAD(0, 1);       // set0 <- chunk 1
    VLOAD(1, 2);       // set1 <- chunk 2
    ALOAD(0, 0);

    #pragma unroll
    for (int c = 0; c < 8; ++c) {
        const int cur = c & 1;
        __syncthreads();
        ALOAD(cur ^ 1, c + 1);
        if (c <= climit) {
            #pragma unroll
            for (int cf = 0; cf < 4; ++cf) {
                bf16x8 bb = *(const bf16x8*)&Bs[cur][cf * 16 + (lane & 15)][ko];
                acc0[cf] = __builtin_amdgcn_mfma_f32_16x16x32_bf16(af0[cur], bb, acc0[cf], 0, 0, 0);
                acc1[cf] = __builtin_amdgcn_mfma_f32_16x16x32_bf16(af1[cur], bb, acc1[cf], 0, 0, 0);
            }
        }
        if (c < 7) BW(cur ^ 1, cur);    // write chunk c+1 (held in set cur)
        if (c < 6) VLOAD(cur, c + 3);   // refill set cur with chunk c+3
    }

    // epilogue: D col = lane&15 (r), row = (lane>>4)*4 + i (t)
    const int dcol  = lane & 15;
    const int drow4 = (lane >> 4) * 4;
    #pragma unroll
    for (int cf = 0; cf < 4; ++cf) {
        const int rg = r0 + cf * 16 + dcol;
        #pragma unroll
        for (int i = 0; i < 4; ++i) {
            const int tg0 = wv * 32 + drow4 + i;
            const int tg1 = tg0 + 16;
            out[((size_t)tg0 * B + b) * R + rg] = acc0[cf][i];
            out[((size_t)tg1 * B + b) * R + rg] = acc1[cf][i];
        }
    }
    #undef VLOAD
    #undef BW
    #undef ALOAD
}

extern "C" void kernel_launch(void* const* d_in, const int* in_sizes, int n_in,
                              void* d_out, int out_size, void* d_ws, size_t ws_size,
                              hipStream_t stream) {
    const float* u  = (const float*)d_in[0];
    const float* d1 = (const float*)d_in[1];
    const float* d2 = (const float*)d_in[2];
    const float* v1 = (const float*)d_in[3];
    const float* v2 = (const float*)d_in[4];
    float* out = (float*)d_out;
    ushort* w  = (ushort*)d_ws;          // 8.39 MB bf16

    weights<<<dim3(T), dim3(256), 0, stream>>>(u, d1, d2, w);
    // grid.x = b (fastest): all r-tiles of a given b land on XCD b%8 -> w L2 reuse
    gemm_mfma<<<dim3(B, R / RT), dim3(256), 0, stream>>>(w, v1, v2, out);
}

// Round 6
// 52.369 us; speedup vs baseline: 1.0527x; 1.0527x over previous
//
#include <hip/hip_runtime.h>
#include <hip/hip_bf16.h>
#include <math.h>

constexpr int T = 128;
constexpr int B = 128;
constexpr int R = 512;
constexpr int NS = 256;   // 2*T slots

typedef __attribute__((ext_vector_type(8))) short bf16x8;
typedef __attribute__((ext_vector_type(4))) float f32x4;

static __device__ __forceinline__ ushort f2bf(float f) {
    union { float f; unsigned u; } v; v.f = f;
    unsigned r = v.u + 0x7fffu + ((v.u >> 16) & 1u);   // RNE
    return (ushort)(r >> 16);
}

// ---------------------------------------------------------------------------
// Kernel 1: closed-form weights, bf16 output. Block = one t, 256 threads.
// (unchanged — measured fast enough; GEMM is the target)
// ---------------------------------------------------------------------------
__global__ __launch_bounds__(256) void weights(
    const float* __restrict__ u, const float* __restrict__ d1,
    const float* __restrict__ d2, ushort* __restrict__ w)
{
    const int t    = blockIdx.x;
    const int tid  = threadIdx.x;
    const int wv   = tid >> 6;
    const int lane = tid & 63;
    __shared__ float eH[T][B];   // 64 KB: e, overwritten with H

    const int nfl = t * B;
    for (int i = tid * 4; i < nfl; i += 1024) {
        const float4 a  = *(const float4*)(d1 + i);
        const float4 b4 = *(const float4*)(d2 + i);
        const float4 c4 = *(const float4*)(u + i);
        *(float4*)(&eH[0][0] + i) =
            make_float4(a.x + b4.x - c4.x, a.y + b4.y - c4.y,
                        a.z + b4.z - c4.z, a.w + b4.w - c4.w);
    }
    __syncthreads();

    if (tid < B) {
        float h = 0.f;
        #pragma unroll 4
        for (int tt = 0; tt < t; ++tt) {
            h = fmaxf(0.f, h + eH[tt][tid]);
            eH[tt][tid] = h;
        }
    }
    __syncthreads();

    const int b0 = lane, b1 = lane + 64;
    const float Ht1a = (t > 0) ? eH[t-1][b0] : 0.f;
    const float Ht1b = (t > 0) ? eH[t-1][b1] : 0.f;
    const float Hpa  = Ht1a + d1[t*B+b0] + d2[t*B+b0];   // H'_t
    const float Hpb  = Ht1b + d1[t*B+b1] + d2[t*B+b1];
    const float Aa   = u[t*B+b0] - Hpa;
    const float Ab   = u[t*B+b1] - Hpb;

    ushort* wrow0 = w + ((size_t)t * B + b0) * NS;
    ushort* wrow1 = w + ((size_t)t * B + b1) * NS;

    const int plo = wv * 32;
    if (plo <= t) {
        const int pe = min(plo + 31, t);
        float ma = 1e30f, mb = 1e30f;
        for (int tau = plo + 32; tau <= t - 1; ++tau) {    // boundary min
            ma = fminf(ma, eH[tau][b0]);
            mb = fminf(mb, eH[tau][b1]);
        }
        float s2a = 0.f, s3a = 0.f, s2b = 0.f, s3b = 0.f;
        float nd1a = d1[pe*B+b0], nd1b = d1[pe*B+b1];
        float nd2a = d2[pe*B+b0], nd2b = d2[pe*B+b1];
        for (int p = pe; p >= plo; --p) {
            const float d1a = nd1a, d1b = nd1b, d2a = nd2a, d2b = nd2b;
            if (p > plo) {
                nd1a = d1[(p-1)*B+b0]; nd1b = d1[(p-1)*B+b1];
                nd2a = d2[(p-1)*B+b0]; nd2b = d2[(p-1)*B+b1];
            }
            if (p < t) { ma = fminf(ma, eH[p][b0]); mb = fminf(mb, eH[p][b1]); }
            const float basea = (p > 0) ? eH[p-1][b0] : 0.f;
            const float baseb = (p > 0) ? eH[p-1][b1] : 0.f;
            const float top0a = basea + d1a, top0b = baseb + d1b;
            const float top1a = top0a + d2a, top1b = top0b + d2b;

            const float sa0 = fminf(fmaxf(ma - basea, 0.f), d1a);
            const float sb0 = fminf(fmaxf(mb - baseb, 0.f), d1b);
            const float sa1 = fminf(fmaxf(ma - top0a, 0.f), d2a);
            const float sb1 = fminf(fmaxf(mb - top0b, 0.f), d2b);

            float cand0 = fmaxf(Aa + fminf(top0a, ma), Ab + fminf(top0b, mb));
            float cand1 = fmaxf(Aa + fminf(top1a, ma), Ab + fminf(top1b, mb));
            #pragma unroll
            for (int off = 32; off >= 1; off >>= 1) {
                cand0 = fmaxf(cand0, __shfl_xor(cand0, off));
                cand1 = fmaxf(cand1, __shfl_xor(cand1, off));
            }

            const float w0a = fminf(sa0, cand0), w0b = fminf(sb0, cand0);
            const float w1a = fminf(sa1, cand1), w1b = fminf(sb1, cand1);
            if (p & 1) { s2a = w0a; s3a = w1a; s2b = w0b; s3b = w1b; }
            else {
                const int g = p >> 1;
                *(ushort4*)(wrow0 + 4*g) =
                    make_ushort4(f2bf(w0a), f2bf(w1a), f2bf(s2a), f2bf(s3a));
                *(ushort4*)(wrow1 + 4*g) =
                    make_ushort4(f2bf(w0b), f2bf(w1b), f2bf(s2b), f2bf(s3b));
            }
        }
    }

    const int gstart = (t >> 1) + 1;
    const int ng = (NS / 4) - gstart;
    if (ng > 0) {
        const ushort4 z = make_ushort4(0, 0, 0, 0);
        const int total = ng * B;
        for (int idx = tid; idx < total; idx += 256) {
            const int gi = idx % ng;
            const int bb = idx / ng;
            *(ushort4*)(w + ((size_t)t*B + bb)*NS + 4*(gstart + gi)) = z;
        }
    }
}

// ---------------------------------------------------------------------------
// Kernel 2: bf16 MFMA GEMM — round-4 structure, 8 waves/block (512 thr).
// Out[t,b,r] = sum_j w[t,b,j] * V[j,b,r]; V interleaved from v1/v2.
// Block = (b, r-tile 128), grid 512 = 2 blocks/CU x 8 waves = 16 waves/CU.
// Wave wv owns t in [16wv, 16wv+16) x 128 r (8 16x16x32 frags, acc 32 VGPR).
// Zero-structure: wave wv skips MFMA for chunk c > wv (44% skipped);
// A-stage rows arow < 16c write zeros instead of loading.
// ---------------------------------------------------------------------------
#define RT 128
__global__ __launch_bounds__(512) void gemm_mfma(
    const ushort* __restrict__ w, const float* __restrict__ v1,
    const float* __restrict__ v2, float* __restrict__ out)
{
    const int b    = blockIdx.x;
    const int r0   = blockIdx.y * RT;
    const int tid  = threadIdx.x;
    const int wv   = tid >> 6;          // 0..7
    const int lane = tid & 63;

    __shared__ ushort As[2][128][40];   // [t][j] bf16, pitch 40
    __shared__ ushort Bs[2][128][40];   // [r][j] bf16 (V transposed)

    // A staging: 4 threads per t-row, each 8 j (16 B)
    const int arow = tid >> 2;          // 0..127
    const int ajh  = (tid & 3) * 8;     // 0,8,16,24
    const ushort* abase = w + ((size_t)arow * B + b) * NS + ajh;

    // B staging: thread = (slot-pair p2 0..15, r-quad rseg 0..31)
    const int p2   = tid & 15;
    const int rseg = tid >> 4;          // 0..31
    const float* v1b = v1 + (size_t)b * R + r0 + rseg * 4;
    const float* v2b = v2 + (size_t)b * R + r0 + rseg * 4;

    f32x4 acc[8];
    const f32x4 zz = {0.f, 0.f, 0.f, 0.f};
    #pragma unroll
    for (int i = 0; i < 8; ++i) acc[i] = zz;

    uint4 la;
    float4 lv1, lv2;

    #define STAGE_LOAD(c) do {                                          \
        if (arow >= 16 * (c)) {                                         \
            la = *(const uint4*)(abase + (c) * 32);                     \
        } else {                                                        \
            la = make_uint4(0u, 0u, 0u, 0u);                            \
        }                                                               \
        const size_t off_ = (size_t)((c) * 16 + p2) * B * R;            \
        lv1 = *(const float4*)(v1b + off_);                             \
        lv2 = *(const float4*)(v2b + off_);                             \
    } while (0)

    #define STAGE_WRITE(buf) do {                                       \
        *(uint4*)&As[buf][arow][ajh] = la;                              \
        const float* f1_ = (const float*)&lv1;                          \
        const float* f2_ = (const float*)&lv2;                          \
        _Pragma("unroll")                                               \
        for (int i_ = 0; i_ < 4; ++i_) {                                \
            unsigned pk_ = (unsigned)f2bf(f1_[i_]) |                    \
                           ((unsigned)f2bf(f2_[i_]) << 16);             \
            *(unsigned*)&Bs[buf][rseg * 4 + i_][p2 * 2] = pk_;          \
        }                                                               \
    } while (0)

    const int tb = wv * 16 + (lane & 15);
    const int ko = (lane >> 4) * 8;

    STAGE_LOAD(0);
    STAGE_WRITE(0);
    #pragma unroll
    for (int c = 0; c < 8; ++c) {
        const int buf = c & 1;
        if (c < 7) STAGE_LOAD(c + 1);
        __syncthreads();
        if (c <= wv) {                  // chunks beyond this are all-zero A
            bf16x8 a0 = *(const bf16x8*)&As[buf][tb][ko];
            #pragma unroll
            for (int cf = 0; cf < 8; ++cf) {
                bf16x8 bb = *(const bf16x8*)&Bs[buf][cf*16 + (lane & 15)][ko];
                acc[cf] = __builtin_amdgcn_mfma_f32_16x16x32_bf16(a0, bb, acc[cf], 0, 0, 0);
            }
        }
        if (c < 7) STAGE_WRITE((c + 1) & 1);
    }

    // epilogue: D col = lane&15 (r), row = (lane>>4)*4 + i (t)
    const int dcol  = lane & 15;
    const int drow4 = (lane >> 4) * 4;
    #pragma unroll
    for (int cf = 0; cf < 8; ++cf) {
        const int rg = r0 + cf * 16 + dcol;
        #pragma unroll
        for (int i = 0; i < 4; ++i) {
            const int tg = wv * 16 + drow4 + i;
            out[((size_t)tg * B + b) * R + rg] = acc[cf][i];
        }
    }
    #undef STAGE_LOAD
    #undef STAGE_WRITE
}

extern "C" void kernel_launch(void* const* d_in, const int* in_sizes, int n_in,
                              void* d_out, int out_size, void* d_ws, size_t ws_size,
                              hipStream_t stream) {
    const float* u  = (const float*)d_in[0];
    const float* d1 = (const float*)d_in[1];
    const float* d2 = (const float*)d_in[2];
    const float* v1 = (const float*)d_in[3];
    const float* v2 = (const float*)d_in[4];
    float* out = (float*)d_out;
    ushort* w  = (ushort*)d_ws;          // 8.39 MB bf16

    weights<<<dim3(T), dim3(256), 0, stream>>>(u, d1, d2, w);
    // grid.x = b (fastest): all r-tiles of a given b land on XCD b%8 -> w L2 reuse
    gemm_mfma<<<dim3(B, R / RT), dim3(512), 0, stream>>>(w, v1, v2, out);
}

// Round 7
// 40.104 us; speedup vs baseline: 1.3746x; 1.3058x over previous
//
#include <hip/hip_runtime.h>
#include <hip/hip_bf16.h>
#include <math.h>

constexpr int T = 128;
constexpr int B = 128;
constexpr int R = 512;
constexpr int NS = 256;   // 2*T slots

typedef __attribute__((ext_vector_type(8))) short bf16x8;
typedef __attribute__((ext_vector_type(4))) float f32x4;

static __device__ __forceinline__ ushort f2bf(float f) {
    union { float f; unsigned u; } v; v.f = f;
    unsigned r = v.u + 0x7fffu + ((v.u >> 16) & 1u);   // RNE
    return (ushort)(r >> 16);
}

// ---------------------------------------------------------------------------
// Kernel 1: closed-form weights, bf16 output. Block = one t, 512 thr (8 waves).
// Phase A0: coalesced stage e = d1+d2-u rows [0,t) into LDS (float4).
// Phase A1: threads 0..127 run H chain from LDS, overwrite e with H in place.
// Phase A2: wave wv computes per-batch min of H over stripe [16wv,16wv+16)∩[0,t)
//           into smin[wv][b] (4 KB LDS) — kills the serial boundary-min loop.
// Phase B : wave wv owns p in [16wv, min(16wv+15,t)]; suffix-min m seeded from
//           smin table (<=7 fmins), then 16 serial iters with 64-lane shfl_xor
//           max for scal. Lane owns batches (lane, lane+64).
// Phase C : zero-fill never-pushed slot groups (bf16 zeros).
// ---------------------------------------------------------------------------
__global__ __launch_bounds__(512) void weights(
    const float* __restrict__ u, const float* __restrict__ d1,
    const float* __restrict__ d2, ushort* __restrict__ w)
{
    const int t    = blockIdx.x;
    const int tid  = threadIdx.x;
    const int wv   = tid >> 6;          // 0..7
    const int lane = tid & 63;
    __shared__ float eH[T][B];          // 64 KB: e, overwritten with H
    __shared__ float smin[8][B];        // 4 KB stripe minima

    // Phase A0
    const int nfl = t * B;
    for (int i = tid * 4; i < nfl; i += 2048) {
        const float4 a  = *(const float4*)(d1 + i);
        const float4 b4 = *(const float4*)(d2 + i);
        const float4 c4 = *(const float4*)(u + i);
        *(float4*)(&eH[0][0] + i) =
            make_float4(a.x + b4.x - c4.x, a.y + b4.y - c4.y,
                        a.z + b4.z - c4.z, a.w + b4.w - c4.w);
    }
    __syncthreads();

    // Phase A1
    if (tid < B) {
        float h = 0.f;
        #pragma unroll 4
        for (int tt = 0; tt < t; ++tt) {
            h = fmaxf(0.f, h + eH[tt][tid]);
            eH[tt][tid] = h;
        }
    }
    __syncthreads();

    const int b0 = lane, b1 = lane + 64;

    // Phase A2: stripe minima (rows up to t-1 matter)
    {
        const int rs = wv * 16;
        const int re = min(rs + 16, t);     // exclusive
        float sa = 1e30f, sb = 1e30f;
        for (int tau = rs; tau < re; ++tau) {
            sa = fminf(sa, eH[tau][b0]);
            sb = fminf(sb, eH[tau][b1]);
        }
        smin[wv][b0] = sa;
        smin[wv][b1] = sb;
    }
    __syncthreads();

    const float Ht1a = (t > 0) ? eH[t-1][b0] : 0.f;
    const float Ht1b = (t > 0) ? eH[t-1][b1] : 0.f;
    const float Hpa  = Ht1a + d1[t*B+b0] + d2[t*B+b0];   // H'_t
    const float Hpb  = Ht1b + d1[t*B+b1] + d2[t*B+b1];
    const float Aa   = u[t*B+b0] - Hpa;
    const float Ab   = u[t*B+b1] - Hpb;

    ushort* wrow0 = w + ((size_t)t * B + b0) * NS;
    ushort* wrow1 = w + ((size_t)t * B + b1) * NS;

    const int plo = wv * 16;
    if (plo <= t) {
        const int pe = min(plo + 15, t);
        float ma = 1e30f, mb = 1e30f;       // seed: min over stripes > wv
        #pragma unroll
        for (int s = 0; s < 8; ++s) {
            if (s > wv) { ma = fminf(ma, smin[s][b0]); mb = fminf(mb, smin[s][b1]); }
        }
        float s2a = 0.f, s3a = 0.f, s2b = 0.f, s3b = 0.f;
        float nd1a = d1[pe*B+b0], nd1b = d1[pe*B+b1];
        float nd2a = d2[pe*B+b0], nd2b = d2[pe*B+b1];
        for (int p = pe; p >= plo; --p) {
            const float d1a = nd1a, d1b = nd1b, d2a = nd2a, d2b = nd2b;
            if (p > plo) {
                nd1a = d1[(p-1)*B+b0]; nd1b = d1[(p-1)*B+b1];
                nd2a = d2[(p-1)*B+b0]; nd2b = d2[(p-1)*B+b1];
            }
            if (p < t) { ma = fminf(ma, eH[p][b0]); mb = fminf(mb, eH[p][b1]); }
            const float basea = (p > 0) ? eH[p-1][b0] : 0.f;
            const float baseb = (p > 0) ? eH[p-1][b1] : 0.f;
            const float top0a = basea + d1a, top0b = baseb + d1b;
            const float top1a = top0a + d2a, top1b = top0b + d2b;

            const float sa0 = fminf(fmaxf(ma - basea, 0.f), d1a);
            const float sb0 = fminf(fmaxf(mb - baseb, 0.f), d1b);
            const float sa1 = fminf(fmaxf(ma - top0a, 0.f), d2a);
            const float sb1 = fminf(fmaxf(mb - top0b, 0.f), d2b);

            float cand0 = fmaxf(Aa + fminf(top0a, ma), Ab + fminf(top0b, mb));
            float cand1 = fmaxf(Aa + fminf(top1a, ma), Ab + fminf(top1b, mb));
            #pragma unroll
            for (int off = 32; off >= 1; off >>= 1) {
                cand0 = fmaxf(cand0, __shfl_xor(cand0, off));
                cand1 = fmaxf(cand1, __shfl_xor(cand1, off));
            }

            const float w0a = fminf(sa0, cand0), w0b = fminf(sb0, cand0);
            const float w1a = fminf(sa1, cand1), w1b = fminf(sb1, cand1);
            if (p & 1) { s2a = w0a; s3a = w1a; s2b = w0b; s3b = w1b; }
            else {
                const int g = p >> 1;
                *(ushort4*)(wrow0 + 4*g) =
                    make_ushort4(f2bf(w0a), f2bf(w1a), f2bf(s2a), f2bf(s3a));
                *(ushort4*)(wrow1 + 4*g) =
                    make_ushort4(f2bf(w0b), f2bf(w1b), f2bf(s2b), f2bf(s3b));
            }
        }
    }

    // Phase C
    const int gstart = (t >> 1) + 1;
    const int ng = (NS / 4) - gstart;
    if (ng > 0) {
        const ushort4 z = make_ushort4(0, 0, 0, 0);
        const int total = ng * B;
        for (int idx = tid; idx < total; idx += 512) {
            const int gi = idx % ng;
            const int bb = idx / ng;
            *(ushort4*)(w + ((size_t)t*B + bb)*NS + 4*(gstart + gi)) = z;
        }
    }
}

// ---------------------------------------------------------------------------
// Kernel 2: bf16 MFMA GEMM — unchanged from round 6 (best measured family).
// ---------------------------------------------------------------------------
#define RT 128
__global__ __launch_bounds__(512) void gemm_mfma(
    const ushort* __restrict__ w, const float* __restrict__ v1,
    const float* __restrict__ v2, float* __restrict__ out)
{
    const int b    = blockIdx.x;
    const int r0   = blockIdx.y * RT;
    const int tid  = threadIdx.x;
    const int wv   = tid >> 6;          // 0..7
    const int lane = tid & 63;

    __shared__ ushort As[2][128][40];   // [t][j] bf16, pitch 40
    __shared__ ushort Bs[2][128][40];   // [r][j] bf16 (V transposed)

    const int arow = tid >> 2;          // 0..127
    const int ajh  = (tid & 3) * 8;     // 0,8,16,24
    const ushort* abase = w + ((size_t)arow * B + b) * NS + ajh;

    const int p2   = tid & 15;
    const int rseg = tid >> 4;          // 0..31
    const float* v1b = v1 + (size_t)b * R + r0 + rseg * 4;
    const float* v2b = v2 + (size_t)b * R + r0 + rseg * 4;

    f32x4 acc[8];
    const f32x4 zz = {0.f, 0.f, 0.f, 0.f};
    #pragma unroll
    for (int i = 0; i < 8; ++i) acc[i] = zz;

    uint4 la;
    float4 lv1, lv2;

    #define STAGE_LOAD(c) do {                                          \
        if (arow >= 16 * (c)) {                                         \
            la = *(const uint4*)(abase + (c) * 32);                     \
        } else {                                                        \
            la = make_uint4(0u, 0u, 0u, 0u);                            \
        }                                                               \
        const size_t off_ = (size_t)((c) * 16 + p2) * B * R;            \
        lv1 = *(const float4*)(v1b + off_);                             \
        lv2 = *(const float4*)(v2b + off_);                             \
    } while (0)

    #define STAGE_WRITE(buf) do {                                       \
        *(uint4*)&As[buf][arow][ajh] = la;                              \
        const float* f1_ = (const float*)&lv1;                          \
        const float* f2_ = (const float*)&lv2;                          \
        _Pragma("unroll")                                               \
        for (int i_ = 0; i_ < 4; ++i_) {                                \
            unsigned pk_ = (unsigned)f2bf(f1_[i_]) |                    \
                           ((unsigned)f2bf(f2_[i_]) << 16);             \
            *(unsigned*)&Bs[buf][rseg * 4 + i_][p2 * 2] = pk_;          \
        }                                                               \
    } while (0)

    const int tb = wv * 16 + (lane & 15);
    const int ko = (lane >> 4) * 8;

    STAGE_LOAD(0);
    STAGE_WRITE(0);
    #pragma unroll
    for (int c = 0; c < 8; ++c) {
        const int buf = c & 1;
        if (c < 7) STAGE_LOAD(c + 1);
        __syncthreads();
        if (c <= wv) {                  // chunks beyond this are all-zero A
            bf16x8 a0 = *(const bf16x8*)&As[buf][tb][ko];
            #pragma unroll
            for (int cf = 0; cf < 8; ++cf) {
                bf16x8 bb = *(const bf16x8*)&Bs[buf][cf*16 + (lane & 15)][ko];
                acc[cf] = __builtin_amdgcn_mfma_f32_16x16x32_bf16(a0, bb, acc[cf], 0, 0, 0);
            }
        }
        if (c < 7) STAGE_WRITE((c + 1) & 1);
    }

    const int dcol  = lane & 15;
    const int drow4 = (lane >> 4) * 4;
    #pragma unroll
    for (int cf = 0; cf < 8; ++cf) {
        const int rg = r0 + cf * 16 + dcol;
        #pragma unroll
        for (int i = 0; i < 4; ++i) {
            const int tg = wv * 16 + drow4 + i;
            out[((size_t)tg * B + b) * R + rg] = acc[cf][i];
        }
    }
    #undef STAGE_LOAD
    #undef STAGE_WRITE
}

extern "C" void kernel_launch(void* const* d_in, const int* in_sizes, int n_in,
                              void* d_out, int out_size, void* d_ws, size_t ws_size,
                              hipStream_t stream) {
    const float* u  = (const float*)d_in[0];
    const float* d1 = (const float*)d_in[1];
    const float* d2 = (const float*)d_in[2];
    const float* v1 = (const float*)d_in[3];
    const float* v2 = (const float*)d_in[4];
    float* out = (float*)d_out;
    ushort* w  = (ushort*)d_ws;          // 8.39 MB bf16

    weights<<<dim3(T), dim3(512), 0, stream>>>(u, d1, d2, w);
    gemm_mfma<<<dim3(B, R / RT), dim3(512), 0, stream>>>(w, v1, v2, out);
}